// Round 2
// baseline (193.570 us; speedup 1.0000x reference)
//
#include <hip/hip_runtime.h>
#include <math.h>

#define BATCH 256
#define DIN   5120
#define RANK  160
#define NS    16
#define NCAT  192   // RANK + NS + NS
#define NSPLIT 40   // k-splits for k1

// ---------------------------------------------------------------------------
// k1a: partial[z] = x(256x5120) @ [W_delta | W_B | W_C] over k-chunk z.
// Split-K (40 chunks of 128), 64x64 tile, 4x4 reg tile. NO atomics.
// ---------------------------------------------------------------------------
__global__ __launch_bounds__(256) void k1a_gemm(
    const float* __restrict__ x, const float* __restrict__ Wd,
    const float* __restrict__ WB, const float* __restrict__ WC,
    float* __restrict__ psum)
{
    __shared__ float xT[32][64];   // [k][m]
    __shared__ float Wt[32][64];   // [k][n]
    const int t  = threadIdx.x;
    const int m0 = blockIdx.x * 64;
    const int n0 = blockIdx.y * 64;
    const int z  = blockIdx.z;
    const int k0 = z * 128;
    const int tm = (t >> 4) * 4;
    const int tn = (t & 15) * 4;

    const int lm  = t >> 2;
    const int lk  = (t & 3) * 8;
    const int ln  = t & 63;
    const int lkb = (t >> 6) * 8;

    const float* wsrc; int wstr;
    {
        const int c = n0 + ln;
        if (c < RANK)            { wsrc = Wd + c;                wstr = RANK; }
        else if (c < RANK + NS)  { wsrc = WB + (c - RANK);       wstr = NS;   }
        else                     { wsrc = WC + (c - RANK - NS);  wstr = NS;   }
    }

    float acc[4][4] = {{0.f}};

    for (int ks = 0; ks < 4; ++ks) {
        const int kb = k0 + ks * 32;
        {
            const float* src = x + (size_t)(m0 + lm) * DIN + kb + lk;
            const float4 a0 = *(const float4*)src;
            const float4 a1 = *(const float4*)(src + 4);
            xT[lk+0][lm]=a0.x; xT[lk+1][lm]=a0.y; xT[lk+2][lm]=a0.z; xT[lk+3][lm]=a0.w;
            xT[lk+4][lm]=a1.x; xT[lk+5][lm]=a1.y; xT[lk+6][lm]=a1.z; xT[lk+7][lm]=a1.w;
        }
        {
            const float* wp = wsrc + (size_t)(kb + lkb) * wstr;
            #pragma unroll
            for (int i = 0; i < 8; ++i) { Wt[lkb + i][ln] = *wp; wp += wstr; }
        }
        __syncthreads();
        #pragma unroll
        for (int k = 0; k < 32; ++k) {
            const float4 a = *(const float4*)&xT[k][tm];
            const float4 b = *(const float4*)&Wt[k][tn];
            acc[0][0] += a.x*b.x; acc[0][1] += a.x*b.y; acc[0][2] += a.x*b.z; acc[0][3] += a.x*b.w;
            acc[1][0] += a.y*b.x; acc[1][1] += a.y*b.y; acc[1][2] += a.y*b.z; acc[1][3] += a.y*b.w;
            acc[2][0] += a.z*b.x; acc[2][1] += a.z*b.y; acc[2][2] += a.z*b.z; acc[2][3] += a.z*b.w;
            acc[3][0] += a.w*b.x; acc[3][1] += a.w*b.y; acc[3][2] += a.w*b.z; acc[3][3] += a.w*b.w;
        }
        __syncthreads();
    }

    float* dst = psum + (size_t)z * (BATCH * NCAT);
    #pragma unroll
    for (int i = 0; i < 4; ++i) {
        const int gm = m0 + tm + i;
        float4 o; o.x = acc[i][0]; o.y = acc[i][1]; o.z = acc[i][2]; o.w = acc[i][3];
        *(float4*)&dst[(size_t)gm * NCAT + n0 + tn] = o;
    }
}

// ---------------------------------------------------------------------------
// k1r: (blocks 0..191) reduce 40 psum partials -> P/Bp/Cc;
//      (all 320 blocks) A2 = -log2(e)*exp(A_log), 81920 elements.
// ---------------------------------------------------------------------------
__global__ __launch_bounds__(256) void k1r_reduce(
    const float* __restrict__ psum, const float* __restrict__ A_log,
    float* __restrict__ P, float* __restrict__ Bp, float* __restrict__ Cc,
    float* __restrict__ A2t)
{
    const int g = blockIdx.x * 256 + threadIdx.x;     // 0..81919
    A2t[g] = -1.442695041f * __expf(A_log[g]);

    if (blockIdx.x < NCAT) {
        const int o = blockIdx.x * 256 + threadIdx.x; // 0..49151
        float s = 0.f;
        #pragma unroll 8
        for (int z = 0; z < NSPLIT; ++z) s += psum[(size_t)z * (BATCH * NCAT) + o];
        const int gm = o / NCAT;
        const int gc = o - gm * NCAT;
        if (gc < RANK)           P [gm * RANK + gc]             = s;
        else if (gc < RANK + NS) Bp[gm * NS   + gc - RANK]      = s;
        else                     Cc[gm * NS   + gc - RANK - NS] = s;
    }
}

__device__ __forceinline__ float softplus20(float z)
{
    if (z > 20.f) return z;
    return fmaxf(z, 0.f) + log1pf(__expf(-fabsf(z)));
}

// ---------------------------------------------------------------------------
// k2_dt: dt = softplus(P @ Wdt + b_dt) -> dtw[256][5120] in workspace.
// Same proven 64x64 LDS-tiled GEMM as before (K=160), grid (80,4).
// ---------------------------------------------------------------------------
__global__ __launch_bounds__(256) void k2_dt(
    const float* __restrict__ P, const float* __restrict__ Wdt,
    const float* __restrict__ bdt, float* __restrict__ dtw)
{
    __shared__ float aT[32][64];    // [k][m] P tile
    __shared__ float Bt[32][64];    // [k][n] Wdt tile

    const int t  = threadIdx.x;
    const int c0 = blockIdx.x * 64;   // 80 channel tiles
    const int b0 = blockIdx.y * 64;   // 4 batch tiles

    const int tm = (t >> 4) * 4;
    const int tn = (t & 15) * 4;
    const int lm  = t >> 2;
    const int lk  = (t & 3) * 8;
    const int ln  = t & 63;
    const int lkb = (t >> 6) * 8;

    float acc[4][4] = {{0.f}};

    for (int ks = 0; ks < 5; ++ks) {
        const int kb = ks * 32;
        {
            const float* src = P + (size_t)(b0 + lm) * RANK + kb + lk;
            const float4 a0 = *(const float4*)src;
            const float4 a1 = *(const float4*)(src + 4);
            aT[lk+0][lm]=a0.x; aT[lk+1][lm]=a0.y; aT[lk+2][lm]=a0.z; aT[lk+3][lm]=a0.w;
            aT[lk+4][lm]=a1.x; aT[lk+5][lm]=a1.y; aT[lk+6][lm]=a1.z; aT[lk+7][lm]=a1.w;
        }
        {
            const float* wp = Wdt + (size_t)(kb + lkb) * DIN + c0 + ln;
            #pragma unroll
            for (int i = 0; i < 8; ++i) { Bt[lkb + i][ln] = wp[(size_t)i * DIN]; }
        }
        __syncthreads();
        #pragma unroll
        for (int k = 0; k < 32; ++k) {
            const float4 a = *(const float4*)&aT[k][tm];
            const float4 b = *(const float4*)&Bt[k][tn];
            acc[0][0] += a.x*b.x; acc[0][1] += a.x*b.y; acc[0][2] += a.x*b.z; acc[0][3] += a.x*b.w;
            acc[1][0] += a.y*b.x; acc[1][1] += a.y*b.y; acc[1][2] += a.y*b.z; acc[1][3] += a.y*b.w;
            acc[2][0] += a.z*b.x; acc[2][1] += a.z*b.y; acc[2][2] += a.z*b.z; acc[2][3] += a.z*b.w;
            acc[3][0] += a.w*b.x; acc[3][1] += a.w*b.y; acc[3][2] += a.w*b.z; acc[3][3] += a.w*b.w;
        }
        __syncthreads();
    }

    const float4 bz = *(const float4*)&bdt[c0 + tn];
    #pragma unroll
    for (int i = 0; i < 4; ++i) {
        float4 o;
        o.x = softplus20(acc[i][0] + bz.x);
        o.y = softplus20(acc[i][1] + bz.y);
        o.z = softplus20(acc[i][2] + bz.z);
        o.w = softplus20(acc[i][3] + bz.w);
        *(float4*)&dtw[(size_t)(b0 + tm + i) * DIN + c0 + tn] = o;
    }
}

// ---------------------------------------------------------------------------
// k3_ssm: SSM update + readout with global_load_lds double-buffered h
// staging (m97 structure). Grid (80,16): block owns 64 channels x 16 batches.
// Tile = 4 batches x 64 ch x 16 n = 16 KB; wave wv stages batch T*4+wv via
// 4x 1KB global_load_lds_dwordx4 (deep async queue, zero VGPR cost). While
// tile T+1 is in flight, compute tile T from LDS: lane owns channel
// c0+lane, full n-sum in-register (A2 row held in 4 float4s, sum(Bp*Cc)
// factored to a per-batch scalar). No shuffles, fully coalesced y store.
// ---------------------------------------------------------------------------
__global__ __launch_bounds__(256) void k3_ssm(
    const float* __restrict__ dtw, const float* __restrict__ x,
    const float* __restrict__ h, const float* __restrict__ A2t,
    const float* __restrict__ Bp, const float* __restrict__ Cc,
    const float* __restrict__ Dv, float* __restrict__ y)
{
    __shared__ float hbuf[2][4096];   // 2 x 16 KB: [buf][u*1024 + chan*16 + n]

    const int t    = threadIdx.x;
    const int lane = t & 63;
    const int wv   = t >> 6;          // wave id, uniform per wave
    const int c0   = blockIdx.x * 64; // 80 channel tiles
    const int b0   = blockIdx.y * 16; // 16 batch groups
    const int c    = c0 + lane;

    // per-lane channel constants: A2 row (16 floats) + D
    const float4* a2p = (const float4*)(A2t + (size_t)c * NS);
    const float4 A20 = a2p[0], A21 = a2p[1], A22 = a2p[2], A23 = a2p[3];
    const float  Dval = Dv[c];

    // stage tile T (batches b0+T*4 .. +3) into hbuf[T&1]; LDS dest is
    // wave-uniform base + lane*16 (hardware), global src is per-lane.
    #define STAGE(T) do {                                                       \
        const float* srcr = h + ((size_t)(b0 + (T)*4 + wv) * DIN + c0) * NS;    \
        float* ldsb = &hbuf[(T)&1][wv * 1024];                                  \
        __builtin_amdgcn_global_load_lds(                                       \
            (const __attribute__((address_space(1))) void*)(srcr + 0*256 + lane*4), \
            (__attribute__((address_space(3))) void*)(ldsb + 0*256), 16, 0, 0); \
        __builtin_amdgcn_global_load_lds(                                       \
            (const __attribute__((address_space(1))) void*)(srcr + 1*256 + lane*4), \
            (__attribute__((address_space(3))) void*)(ldsb + 1*256), 16, 0, 0); \
        __builtin_amdgcn_global_load_lds(                                       \
            (const __attribute__((address_space(1))) void*)(srcr + 2*256 + lane*4), \
            (__attribute__((address_space(3))) void*)(ldsb + 2*256), 16, 0, 0); \
        __builtin_amdgcn_global_load_lds(                                       \
            (const __attribute__((address_space(1))) void*)(srcr + 3*256 + lane*4), \
            (__attribute__((address_space(3))) void*)(ldsb + 3*256), 16, 0, 0); \
    } while (0)

    STAGE(0);
    __syncthreads();   // implicit vmcnt(0) drain -> tile 0 resident

    #pragma unroll
    for (int T = 0; T < 4; ++T) {
        if (T < 3) STAGE(T + 1);          // async into the other buffer

        #pragma unroll
        for (int u = 0; u < 4; ++u) {
            const int b = b0 + T * 4 + u;
            const size_t bc = (size_t)b * DIN + c;
            const float dtv = dtw[bc];
            const float xv  = x[bc];
            const float4* bp4 = (const float4*)(Bp + b * NS);
            const float4* cc4 = (const float4*)(Cc + b * NS);
            const float4 Bq0 = bp4[0], Bq1 = bp4[1], Bq2 = bp4[2], Bq3 = bp4[3];
            const float4 Cq0 = cc4[0], Cq1 = cc4[1], Cq2 = cc4[2], Cq3 = cc4[3];

            const float4* hv = (const float4*)&hbuf[T & 1][u * 1024 + lane * 16];
            const float4 h0 = hv[0], h1 = hv[1], h2 = hv[2], h3 = hv[3];

            float sbc;
            sbc  = Bq0.x*Cq0.x + Bq0.y*Cq0.y + Bq0.z*Cq0.z + Bq0.w*Cq0.w;
            sbc += Bq1.x*Cq1.x + Bq1.y*Cq1.y + Bq1.z*Cq1.z + Bq1.w*Cq1.w;
            sbc += Bq2.x*Cq2.x + Bq2.y*Cq2.y + Bq2.z*Cq2.z + Bq2.w*Cq2.w;
            sbc += Bq3.x*Cq3.x + Bq3.y*Cq3.y + Bq3.z*Cq3.z + Bq3.w*Cq3.w;

            float s = xv * (dtv * sbc + Dval);
            s += exp2f(dtv * A20.x) * h0.x * Cq0.x;
            s += exp2f(dtv * A20.y) * h0.y * Cq0.y;
            s += exp2f(dtv * A20.z) * h0.z * Cq0.z;
            s += exp2f(dtv * A20.w) * h0.w * Cq0.w;
            s += exp2f(dtv * A21.x) * h1.x * Cq1.x;
            s += exp2f(dtv * A21.y) * h1.y * Cq1.y;
            s += exp2f(dtv * A21.z) * h1.z * Cq1.z;
            s += exp2f(dtv * A21.w) * h1.w * Cq1.w;
            s += exp2f(dtv * A22.x) * h2.x * Cq2.x;
            s += exp2f(dtv * A22.y) * h2.y * Cq2.y;
            s += exp2f(dtv * A22.z) * h2.z * Cq2.z;
            s += exp2f(dtv * A22.w) * h2.w * Cq2.w;
            s += exp2f(dtv * A23.x) * h3.x * Cq3.x;
            s += exp2f(dtv * A23.y) * h3.y * Cq3.y;
            s += exp2f(dtv * A23.z) * h3.z * Cq3.z;
            s += exp2f(dtv * A23.w) * h3.w * Cq3.w;

            y[bc] = s;
        }
        __syncthreads();  // drains vmcnt -> tile T+1 resident; protects buf reuse
    }
    #undef STAGE
}

// ---------------------------------------------------------------------------
extern "C" void kernel_launch(void* const* d_in, const int* in_sizes, int n_in,
                              void* d_out, int out_size, void* d_ws, size_t ws_size,
                              hipStream_t stream)
{
    const float* x     = (const float*)d_in[0];
    const float* h     = (const float*)d_in[1];
    const float* Wd    = (const float*)d_in[2];
    const float* Wdt   = (const float*)d_in[3];
    const float* bdt   = (const float*)d_in[4];
    const float* A_log = (const float*)d_in[5];
    const float* WB    = (const float*)d_in[6];
    const float* WC    = (const float*)d_in[7];
    const float* Dv    = (const float*)d_in[8];
    float* out = (float*)d_out;

    // ws layout (floats): psum (40x256x192) | P | Bp | Cc | A2 (5120x16)
    // dtw (256x5120) ALIASES psum: psum is dead after k1r, k2 runs after.
    float* psum = (float*)d_ws;
    float* dtw  = psum;
    float* P    = psum + (size_t)NSPLIT * BATCH * NCAT;
    float* Bp   = P  + BATCH * RANK;
    float* Cc   = Bp + BATCH * NS;
    float* A2t  = Cc + BATCH * NS;

    // no memset needed: every ws word is written before it is read
    k1a_gemm  <<<dim3(4, 3, NSPLIT), 256, 0, stream>>>(x, Wd, WB, WC, psum);
    k1r_reduce<<<dim3(320),          256, 0, stream>>>(psum, A_log, P, Bp, Cc, A2t);
    k2_dt     <<<dim3(80, 4),        256, 0, stream>>>(P, Wdt, bdt, dtw);
    k3_ssm    <<<dim3(80, 16),       256, 0, stream>>>(dtw, x, h, A2t, Bp, Cc, Dv, out);
}

// Round 3
// 174.518 us; speedup vs baseline: 1.1092x; 1.1092x over previous
//
#include <hip/hip_runtime.h>
#include <math.h>

#define BATCH 256
#define DIN   5120
#define RANK  160
#define NS    16
#define NCAT  192   // RANK + NS + NS
#define NSPLIT 40   // k-splits for k1

// ---------------------------------------------------------------------------
// k1a: partial[z] = x(256x5120) @ [W_delta | W_B | W_C] over k-chunk z.
// Split-K (40 chunks of 128), 64x64 tile, 4x4 reg tile. NO atomics.
// ---------------------------------------------------------------------------
__global__ __launch_bounds__(256) void k1a_gemm(
    const float* __restrict__ x, const float* __restrict__ Wd,
    const float* __restrict__ WB, const float* __restrict__ WC,
    float* __restrict__ psum)
{
    __shared__ float xT[32][64];   // [k][m]
    __shared__ float Wt[32][64];   // [k][n]
    const int t  = threadIdx.x;
    const int m0 = blockIdx.x * 64;
    const int n0 = blockIdx.y * 64;
    const int z  = blockIdx.z;
    const int k0 = z * 128;
    const int tm = (t >> 4) * 4;
    const int tn = (t & 15) * 4;

    const int lm  = t >> 2;
    const int lk  = (t & 3) * 8;
    const int ln  = t & 63;
    const int lkb = (t >> 6) * 8;

    const float* wsrc; int wstr;
    {
        const int c = n0 + ln;
        if (c < RANK)            { wsrc = Wd + c;                wstr = RANK; }
        else if (c < RANK + NS)  { wsrc = WB + (c - RANK);       wstr = NS;   }
        else                     { wsrc = WC + (c - RANK - NS);  wstr = NS;   }
    }

    float acc[4][4] = {{0.f}};

    for (int ks = 0; ks < 4; ++ks) {
        const int kb = k0 + ks * 32;
        {
            const float* src = x + (size_t)(m0 + lm) * DIN + kb + lk;
            const float4 a0 = *(const float4*)src;
            const float4 a1 = *(const float4*)(src + 4);
            xT[lk+0][lm]=a0.x; xT[lk+1][lm]=a0.y; xT[lk+2][lm]=a0.z; xT[lk+3][lm]=a0.w;
            xT[lk+4][lm]=a1.x; xT[lk+5][lm]=a1.y; xT[lk+6][lm]=a1.z; xT[lk+7][lm]=a1.w;
        }
        {
            const float* wp = wsrc + (size_t)(kb + lkb) * wstr;
            #pragma unroll
            for (int i = 0; i < 8; ++i) { Wt[lkb + i][ln] = *wp; wp += wstr; }
        }
        __syncthreads();
        #pragma unroll
        for (int k = 0; k < 32; ++k) {
            const float4 a = *(const float4*)&xT[k][tm];
            const float4 b = *(const float4*)&Wt[k][tn];
            acc[0][0] += a.x*b.x; acc[0][1] += a.x*b.y; acc[0][2] += a.x*b.z; acc[0][3] += a.x*b.w;
            acc[1][0] += a.y*b.x; acc[1][1] += a.y*b.y; acc[1][2] += a.y*b.z; acc[1][3] += a.y*b.w;
            acc[2][0] += a.z*b.x; acc[2][1] += a.z*b.y; acc[2][2] += a.z*b.z; acc[2][3] += a.z*b.w;
            acc[3][0] += a.w*b.x; acc[3][1] += a.w*b.y; acc[3][2] += a.w*b.z; acc[3][3] += a.w*b.w;
        }
        __syncthreads();
    }

    float* dst = psum + (size_t)z * (BATCH * NCAT);
    #pragma unroll
    for (int i = 0; i < 4; ++i) {
        const int gm = m0 + tm + i;
        float4 o; o.x = acc[i][0]; o.y = acc[i][1]; o.z = acc[i][2]; o.w = acc[i][3];
        *(float4*)&dst[(size_t)gm * NCAT + n0 + tn] = o;
    }
}

// ---------------------------------------------------------------------------
// k1r: reduce 40 psum partials -> P/Bp/Cc. 192 blocks x 256 threads.
// (A2 derivation moved into k3 — saves a full pass + 328 KB ws array.)
// ---------------------------------------------------------------------------
__global__ __launch_bounds__(256) void k1r_reduce(
    const float* __restrict__ psum,
    float* __restrict__ P, float* __restrict__ Bp, float* __restrict__ Cc)
{
    const int o = blockIdx.x * 256 + threadIdx.x; // 0..49151
    float s = 0.f;
    #pragma unroll 8
    for (int z = 0; z < NSPLIT; ++z) s += psum[(size_t)z * (BATCH * NCAT) + o];
    const int gm = o / NCAT;
    const int gc = o - gm * NCAT;
    if (gc < RANK)           P [gm * RANK + gc]             = s;
    else if (gc < RANK + NS) Bp[gm * NS   + gc - RANK]      = s;
    else                     Cc[gm * NS   + gc - RANK - NS] = s;
}

__device__ __forceinline__ float softplus20(float z)
{
    if (z > 20.f) return z;
    return fmaxf(z, 0.f) + log1pf(__expf(-fabsf(z)));
}

// ---------------------------------------------------------------------------
// k3_ssm: fused dt-GEMM + SSM. Grid (80,16): block = 64 channels x 16 batches,
// 4 waves. Phase A: dt[16][64] = softplus(P[16][160] @ Wdt[160][64] + b) via
// LDS-staged ks-loop (P tile flat-copied 10 KB, Wdt tile proven 8-row stage);
// wave wv computes batches wv*4..+3, lane = channel. Phase B: round-1 proven
// coalesced h-stream: lane 4j+v covers channel c0+q*16+j, states 4v..4v+3;
// h loads 1 KB/instr; A2 derived in-register from A_log (16 expf/lane once);
// 4-lane shfl_xor n-sum; coalesced 256 B y store per batch.
// ---------------------------------------------------------------------------
__global__ __launch_bounds__(256) void k3_ssm(
    const float* __restrict__ P, const float* __restrict__ Wdt,
    const float* __restrict__ bdt, const float* __restrict__ x,
    const float* __restrict__ h, const float* __restrict__ A_log,
    const float* __restrict__ Bp, const float* __restrict__ Cc,
    const float* __restrict__ Dv, float* __restrict__ y)
{
    __shared__ float sP[16 * RANK];   // 10 KB: P rows b0..b0+15, flat [b*160+k]
    __shared__ float Bt[32][64];      //  8 KB: Wdt k-tile
    __shared__ float sdt[16][64];     //  4 KB: dt tile [b_local][c_local]

    const int t    = threadIdx.x;
    const int lane = t & 63;
    const int wv   = t >> 6;          // wave id
    const int c0   = blockIdx.x * 64; // 80 channel tiles
    const int b0   = blockIdx.y * 16; // 16 batch tiles

    // ---- phase A: dt tile (M=16 batches, N=64 channels, K=160) ----
    {
        // flat coalesced copy of P rows b0..b0+15 (2560 floats)
        const float* Pb = P + (size_t)b0 * RANK;
        #pragma unroll
        for (int i = 0; i < 10; ++i) sP[i * 256 + t] = Pb[i * 256 + t];

        const int ln  = lane;
        const int lkb = wv * 8;
        float acc[4] = {0.f, 0.f, 0.f, 0.f};

        for (int ks = 0; ks < 5; ++ks) {
            const int kb = ks * 32;
            {
                const float* wp = Wdt + (size_t)(kb + lkb) * DIN + c0 + ln;
                #pragma unroll
                for (int i = 0; i < 8; ++i) Bt[lkb + i][ln] = wp[(size_t)i * DIN];
            }
            __syncthreads();
            #pragma unroll
            for (int k = 0; k < 32; ++k) {
                const float w = Bt[k][lane];
                acc[0] += sP[(wv * 4 + 0) * RANK + kb + k] * w;
                acc[1] += sP[(wv * 4 + 1) * RANK + kb + k] * w;
                acc[2] += sP[(wv * 4 + 2) * RANK + kb + k] * w;
                acc[3] += sP[(wv * 4 + 3) * RANK + kb + k] * w;
            }
            __syncthreads();
        }

        const float bz = bdt[c0 + lane];
        #pragma unroll
        for (int i = 0; i < 4; ++i)
            sdt[wv * 4 + i][lane] = softplus20(acc[i] + bz);
    }
    __syncthreads();

    // ---- phase B: SSM update + readout ----
    const int v = lane & 3;     // state quad: n = 4v..4v+3
    const int j = lane >> 2;    // channel within 16

    // per-lane channel constants: A2 = -log2(e)*exp(A_log) (16 per lane) + D
    float4 A2q[4]; float dvq[4];
    #pragma unroll
    for (int q = 0; q < 4; ++q) {
        const int c = c0 + q * 16 + j;
        const float4 al = *(const float4*)(A_log + (size_t)c * NS + v * 4);
        A2q[q].x = -1.442695041f * __expf(al.x);
        A2q[q].y = -1.442695041f * __expf(al.y);
        A2q[q].z = -1.442695041f * __expf(al.z);
        A2q[q].w = -1.442695041f * __expf(al.w);
        dvq[q] = Dv[c];
    }

    #pragma unroll
    for (int bi = 0; bi < 4; ++bi) {
        const int bl = wv * 4 + bi;
        const int gb = b0 + bl;
        const float4 B4 = *(const float4*)(Bp + gb * NS + v * 4);
        const float4 C4 = *(const float4*)(Cc + gb * NS + v * 4);
        float res[4];
        #pragma unroll
        for (int q = 0; q < 4; ++q) {
            const int c = c0 + q * 16 + j;
            const float dtv = sdt[bl][q * 16 + j];
            const float xv  = x[(size_t)gb * DIN + c];
            const float dtx = dtv * xv;
            const float4 h4 = *(const float4*)(h + ((size_t)gb * DIN + c) * NS + v * 4);
            float s;
            s  = (exp2f(dtv * A2q[q].x) * h4.x + dtx * B4.x) * C4.x;
            s += (exp2f(dtv * A2q[q].y) * h4.y + dtx * B4.y) * C4.y;
            s += (exp2f(dtv * A2q[q].z) * h4.z + dtx * B4.z) * C4.z;
            s += (exp2f(dtv * A2q[q].w) * h4.w + dtx * B4.w) * C4.w;
            if (v == 0) s += xv * dvq[q];
            res[q] = s;
        }
        #pragma unroll
        for (int q = 0; q < 4; ++q) {
            res[q] += __shfl_xor(res[q], 1, 64);
            res[q] += __shfl_xor(res[q], 2, 64);
        }
        // all lanes hold res[0..3]; lane 4j+v stores channel c0+v*16+j
        const float out = (v == 0) ? res[0] : (v == 1) ? res[1]
                        : (v == 2) ? res[2] : res[3];
        y[(size_t)gb * DIN + c0 + v * 16 + j] = out;
    }
}

// ---------------------------------------------------------------------------
extern "C" void kernel_launch(void* const* d_in, const int* in_sizes, int n_in,
                              void* d_out, int out_size, void* d_ws, size_t ws_size,
                              hipStream_t stream)
{
    const float* x     = (const float*)d_in[0];
    const float* h     = (const float*)d_in[1];
    const float* Wd    = (const float*)d_in[2];
    const float* Wdt   = (const float*)d_in[3];
    const float* bdt   = (const float*)d_in[4];
    const float* A_log = (const float*)d_in[5];
    const float* WB    = (const float*)d_in[6];
    const float* WC    = (const float*)d_in[7];
    const float* Dv    = (const float*)d_in[8];
    float* out = (float*)d_out;

    // ws layout (floats): psum (40x256x192) | P (256x160) | Bp | Cc
    float* psum = (float*)d_ws;
    float* P    = psum + (size_t)NSPLIT * BATCH * NCAT;
    float* Bp   = P  + BATCH * RANK;
    float* Cc   = Bp + BATCH * NS;

    // no memset needed: every ws word is written before it is read
    k1a_gemm  <<<dim3(4, 3, NSPLIT), 256, 0, stream>>>(x, Wd, WB, WC, psum);
    k1r_reduce<<<dim3(NCAT),         256, 0, stream>>>(psum, P, Bp, Cc);
    k3_ssm    <<<dim3(80, 16),       256, 0, stream>>>(P, Wdt, bdt, x, h, A_log,
                                                       Bp, Cc, Dv, out);
}

// Round 6
// 174.083 us; speedup vs baseline: 1.1119x; 1.0025x over previous
//
#include <hip/hip_runtime.h>
#include <math.h>

#define BATCH 256
#define DIN   5120
#define RANK  160
#define NS    16
#define NCAT  192   // RANK + NS + NS
#define NSPLIT 40   // k-splits for k1

// ---------------------------------------------------------------------------
// k1a: partial[z] = x(256x5120) @ [W_delta | W_B | W_C] over k-chunk z.
// Split-K (40 chunks of 128), 64x64 tile, 4x4 reg tile. NO atomics.
// (UNCHANGED.)
// ---------------------------------------------------------------------------
__global__ __launch_bounds__(256) void k1a_gemm(
    const float* __restrict__ x, const float* __restrict__ Wd,
    const float* __restrict__ WB, const float* __restrict__ WC,
    float* __restrict__ psum)
{
    __shared__ float xT[32][64];   // [k][m]
    __shared__ float Wt[32][64];   // [k][n]
    const int t  = threadIdx.x;
    const int m0 = blockIdx.x * 64;
    const int n0 = blockIdx.y * 64;
    const int z  = blockIdx.z;
    const int k0 = z * 128;
    const int tm = (t >> 4) * 4;
    const int tn = (t & 15) * 4;

    const int lm  = t >> 2;
    const int lk  = (t & 3) * 8;
    const int ln  = t & 63;
    const int lkb = (t >> 6) * 8;

    const float* wsrc; int wstr;
    {
        const int c = n0 + ln;
        if (c < RANK)            { wsrc = Wd + c;                wstr = RANK; }
        else if (c < RANK + NS)  { wsrc = WB + (c - RANK);       wstr = NS;   }
        else                     { wsrc = WC + (c - RANK - NS);  wstr = NS;   }
    }

    float acc[4][4] = {{0.f}};

    for (int ks = 0; ks < 4; ++ks) {
        const int kb = k0 + ks * 32;
        {
            const float* src = x + (size_t)(m0 + lm) * DIN + kb + lk;
            const float4 a0 = *(const float4*)src;
            const float4 a1 = *(const float4*)(src + 4);
            xT[lk+0][lm]=a0.x; xT[lk+1][lm]=a0.y; xT[lk+2][lm]=a0.z; xT[lk+3][lm]=a0.w;
            xT[lk+4][lm]=a1.x; xT[lk+5][lm]=a1.y; xT[lk+6][lm]=a1.z; xT[lk+7][lm]=a1.w;
        }
        {
            const float* wp = wsrc + (size_t)(kb + lkb) * wstr;
            #pragma unroll
            for (int i = 0; i < 8; ++i) { Wt[lkb + i][ln] = *wp; wp += wstr; }
        }
        __syncthreads();
        #pragma unroll
        for (int k = 0; k < 32; ++k) {
            const float4 a = *(const float4*)&xT[k][tm];
            const float4 b = *(const float4*)&Wt[k][tn];
            acc[0][0] += a.x*b.x; acc[0][1] += a.x*b.y; acc[0][2] += a.x*b.z; acc[0][3] += a.x*b.w;
            acc[1][0] += a.y*b.x; acc[1][1] += a.y*b.y; acc[1][2] += a.y*b.z; acc[1][3] += a.y*b.w;
            acc[2][0] += a.z*b.x; acc[2][1] += a.z*b.y; acc[2][2] += a.z*b.z; acc[2][3] += a.z*b.w;
            acc[3][0] += a.w*b.x; acc[3][1] += a.w*b.y; acc[3][2] += a.w*b.z; acc[3][3] += a.w*b.w;
        }
        __syncthreads();
    }

    float* dst = psum + (size_t)z * (BATCH * NCAT);
    #pragma unroll
    for (int i = 0; i < 4; ++i) {
        const int gm = m0 + tm + i;
        float4 o; o.x = acc[i][0]; o.y = acc[i][1]; o.z = acc[i][2]; o.w = acc[i][3];
        *(float4*)&dst[(size_t)gm * NCAT + n0 + tn] = o;
    }
}

// ---------------------------------------------------------------------------
// k1r: reduce 40 psum partials -> P/Bp/Cc. 192 blocks x 256 threads.
// (UNCHANGED.)
// ---------------------------------------------------------------------------
__global__ __launch_bounds__(256) void k1r_reduce(
    const float* __restrict__ psum,
    float* __restrict__ P, float* __restrict__ Bp, float* __restrict__ Cc)
{
    const int o = blockIdx.x * 256 + threadIdx.x; // 0..49151
    float s = 0.f;
    #pragma unroll 8
    for (int z = 0; z < NSPLIT; ++z) s += psum[(size_t)z * (BATCH * NCAT) + o];
    const int gm = o / NCAT;
    const int gc = o - gm * NCAT;
    if (gc < RANK)           P [gm * RANK + gc]             = s;
    else if (gc < RANK + NS) Bp[gm * NS   + gc - RANK]      = s;
    else                     Cc[gm * NS   + gc - RANK - NS] = s;
}

__device__ __forceinline__ float softplus20(float z)
{
    if (z > 20.f) return z;
    return fmaxf(z, 0.f) + log1pf(__expf(-fabsf(z)));
}

// ---------------------------------------------------------------------------
// k3_ssm: fused dt-GEMM + SSM. Grid (80,16): block = 64 channels x 16 batches.
// Phase A (unchanged, proven): dt[16][64] = softplus(P@Wdt + b) via LDS tiles.
// Phase B: explicit load-batching to force ILP. Per wave, its 4 batches are
// processed as two 2-batch groups; per group ALL global loads (8x 1KB-
// coalesced h float4, 2x coalesced x row-loads, B/C quads) are issued into
// named registers BEFORE any use. h sub-block stride is q*256 floats
// (16 ch x 16 states). lane*4 = 16j+4v matches (q*16+j)*16 + 4v layout.
// ---------------------------------------------------------------------------
__global__ __launch_bounds__(256) void k3_ssm(
    const float* __restrict__ P, const float* __restrict__ Wdt,
    const float* __restrict__ bdt, const float* __restrict__ x,
    const float* __restrict__ h, const float* __restrict__ A_log,
    const float* __restrict__ Bp, const float* __restrict__ Cc,
    const float* __restrict__ Dv, float* __restrict__ y)
{
    __shared__ float sP[16 * RANK];   // 10 KB: P rows b0..b0+15, flat [b*160+k]
    __shared__ float Bt[32][64];      //  8 KB: Wdt k-tile
    __shared__ float sdt[16][64];     //  4 KB: dt tile [b_local][c_local]

    const int t    = threadIdx.x;
    const int lane = t & 63;
    const int wv   = t >> 6;          // wave id
    const int c0   = blockIdx.x * 64; // 80 channel tiles
    const int b0   = blockIdx.y * 16; // 16 batch tiles

    // ---- phase A: dt tile (M=16 batches, N=64 channels, K=160) ----
    {
        const float* Pb = P + (size_t)b0 * RANK;
        #pragma unroll
        for (int i = 0; i < 10; ++i) sP[i * 256 + t] = Pb[i * 256 + t];

        const int ln  = lane;
        const int lkb = wv * 8;
        float acc[4] = {0.f, 0.f, 0.f, 0.f};

        for (int ks = 0; ks < 5; ++ks) {
            const int kb = ks * 32;
            {
                const float* wp = Wdt + (size_t)(kb + lkb) * DIN + c0 + ln;
                #pragma unroll
                for (int i = 0; i < 8; ++i) Bt[lkb + i][ln] = wp[(size_t)i * DIN];
            }
            __syncthreads();
            #pragma unroll
            for (int k = 0; k < 32; ++k) {
                const float w = Bt[k][lane];
                acc[0] += sP[(wv * 4 + 0) * RANK + kb + k] * w;
                acc[1] += sP[(wv * 4 + 1) * RANK + kb + k] * w;
                acc[2] += sP[(wv * 4 + 2) * RANK + kb + k] * w;
                acc[3] += sP[(wv * 4 + 3) * RANK + kb + k] * w;
            }
            __syncthreads();
        }

        const float bz = bdt[c0 + lane];
        #pragma unroll
        for (int i = 0; i < 4; ++i)
            sdt[wv * 4 + i][lane] = softplus20(acc[i] + bz);
    }
    __syncthreads();

    // ---- phase B: SSM update + readout ----
    const int v = lane & 3;     // state quad: n = 4v..4v+3
    const int j = lane >> 2;    // channel within 16

    // per-lane channel constants: A2 = -log2(e)*exp(A_log) (16 per lane) + D
    float4 A2q[4]; float dvq[4];
    #pragma unroll
    for (int q = 0; q < 4; ++q) {
        const int c = c0 + q * 16 + j;
        const float4 al = *(const float4*)(A_log + (size_t)c * NS + v * 4);
        A2q[q].x = -1.442695041f * __expf(al.x);
        A2q[q].y = -1.442695041f * __expf(al.y);
        A2q[q].z = -1.442695041f * __expf(al.z);
        A2q[q].w = -1.442695041f * __expf(al.w);
        dvq[q] = Dv[c];
    }

    #pragma unroll
    for (int g = 0; g < 2; ++g) {
        const int bl0 = wv * 4 + g * 2;     // local batch pair
        const int gb0 = b0 + bl0;
        const int gb1 = gb0 + 1;

        // ---- issue ALL global loads for both batches (named regs) ----
        // h tile for (batch, c0..c0+63) = 1024 floats; q sub-block = q*256.
        const size_t hb0 = ((size_t)gb0 * DIN + c0) * NS;
        const size_t hb1 = ((size_t)gb1 * DIN + c0) * NS;
        const float4 h00 = *(const float4*)(h + hb0 +   0 + lane * 4);
        const float4 h01 = *(const float4*)(h + hb0 + 256 + lane * 4);
        const float4 h02 = *(const float4*)(h + hb0 + 512 + lane * 4);
        const float4 h03 = *(const float4*)(h + hb0 + 768 + lane * 4);
        const float4 h10 = *(const float4*)(h + hb1 +   0 + lane * 4);
        const float4 h11 = *(const float4*)(h + hb1 + 256 + lane * 4);
        const float4 h12 = *(const float4*)(h + hb1 + 512 + lane * 4);
        const float4 h13 = *(const float4*)(h + hb1 + 768 + lane * 4);
        const float  xr0 = x[(size_t)gb0 * DIN + c0 + lane];
        const float  xr1 = x[(size_t)gb1 * DIN + c0 + lane];
        const float4 B40 = *(const float4*)(Bp + gb0 * NS + v * 4);
        const float4 C40 = *(const float4*)(Cc + gb0 * NS + v * 4);
        const float4 B41 = *(const float4*)(Bp + gb1 * NS + v * 4);
        const float4 C41 = *(const float4*)(Cc + gb1 * NS + v * 4);

        // ---- batch 0 ----
        float res0[4];
        #pragma unroll
        for (int q = 0; q < 4; ++q) {
            const float dtv = sdt[bl0][q * 16 + j];
            const float xv  = __shfl(xr0, q * 16 + j, 64);
            const float dtx = dtv * xv;
            const float4 hv = (q == 0) ? h00 : (q == 1) ? h01 : (q == 2) ? h02 : h03;
            float s;
            s  = (exp2f(dtv * A2q[q].x) * hv.x + dtx * B40.x) * C40.x;
            s += (exp2f(dtv * A2q[q].y) * hv.y + dtx * B40.y) * C40.y;
            s += (exp2f(dtv * A2q[q].z) * hv.z + dtx * B40.z) * C40.z;
            s += (exp2f(dtv * A2q[q].w) * hv.w + dtx * B40.w) * C40.w;
            if (v == 0) s += xv * dvq[q];
            res0[q] = s;
        }

        // ---- batch 1 ----
        float res1[4];
        #pragma unroll
        for (int q = 0; q < 4; ++q) {
            const float dtv = sdt[bl0 + 1][q * 16 + j];
            const float xv  = __shfl(xr1, q * 16 + j, 64);
            const float dtx = dtv * xv;
            const float4 hv = (q == 0) ? h10 : (q == 1) ? h11 : (q == 2) ? h12 : h13;
            float s;
            s  = (exp2f(dtv * A2q[q].x) * hv.x + dtx * B41.x) * C41.x;
            s += (exp2f(dtv * A2q[q].y) * hv.y + dtx * B41.y) * C41.y;
            s += (exp2f(dtv * A2q[q].z) * hv.z + dtx * B41.z) * C41.z;
            s += (exp2f(dtv * A2q[q].w) * hv.w + dtx * B41.w) * C41.w;
            if (v == 0) s += xv * dvq[q];
            res1[q] = s;
        }

        // ---- 4-lane n-sum + coalesced stores ----
        #pragma unroll
        for (int q = 0; q < 4; ++q) {
            res0[q] += __shfl_xor(res0[q], 1, 64);
            res0[q] += __shfl_xor(res0[q], 2, 64);
            res1[q] += __shfl_xor(res1[q], 1, 64);
            res1[q] += __shfl_xor(res1[q], 2, 64);
        }
        const float out0 = (v == 0) ? res0[0] : (v == 1) ? res0[1]
                         : (v == 2) ? res0[2] : res0[3];
        const float out1 = (v == 0) ? res1[0] : (v == 1) ? res1[1]
                         : (v == 2) ? res1[2] : res1[3];
        y[(size_t)gb0 * DIN + c0 + v * 16 + j] = out0;
        y[(size_t)gb1 * DIN + c0 + v * 16 + j] = out1;
    }
}

// ---------------------------------------------------------------------------
extern "C" void kernel_launch(void* const* d_in, const int* in_sizes, int n_in,
                              void* d_out, int out_size, void* d_ws, size_t ws_size,
                              hipStream_t stream)
{
    const float* x     = (const float*)d_in[0];
    const float* h     = (const float*)d_in[1];
    const float* Wd    = (const float*)d_in[2];
    const float* Wdt   = (const float*)d_in[3];
    const float* bdt   = (const float*)d_in[4];
    const float* A_log = (const float*)d_in[5];
    const float* WB    = (const float*)d_in[6];
    const float* WC    = (const float*)d_in[7];
    const float* Dv    = (const float*)d_in[8];
    float* out = (float*)d_out;

    // ws layout (floats): psum (40x256x192) | P (256x160) | Bp | Cc
    float* psum = (float*)d_ws;
    float* P    = psum + (size_t)NSPLIT * BATCH * NCAT;
    float* Bp   = P  + BATCH * RANK;
    float* Cc   = Bp + BATCH * NS;

    // no memset needed: every ws word is written before it is read
    k1a_gemm  <<<dim3(4, 3, NSPLIT), 256, 0, stream>>>(x, Wd, WB, WC, psum);
    k1r_reduce<<<dim3(NCAT),         256, 0, stream>>>(psum, P, Bp, Cc);
    k3_ssm    <<<dim3(80, 16),       256, 0, stream>>>(P, Wdt, bdt, x, h, A_log,
                                                       Bp, Cc, Dv, out);
}